// Round 2
// baseline (1843.042 us; speedup 1.0000x reference)
//
#include <hip/hip_runtime.h>
#include <cstdint>
#include <cstddef>

// Problem dims
constexpr int U_N = 8192;
constexpr int I_N = 6144;

// Output layout (flat float offsets), reference return order:
// (u_g, i_g, item_feats[2,I,D], user_feats[2,U,D], u_g, i_g, user_ids[2,U,D], item_ids[2,I,D])
constexpr size_t UD  = (size_t)U_N * 64;
constexpr size_t IDD = (size_t)I_N * 64;
constexpr size_t O1 = 0;
constexpr size_t O2 = O1 + UD;
constexpr size_t O3 = O2 + IDD;
constexpr size_t O4 = O3 + 2 * IDD;
constexpr size_t O5 = O4 + 2 * UD;
constexpr size_t O6 = O5 + UD;
constexpr size_t O7 = O6 + IDD;
constexpr size_t O8 = O7 + 2 * UD;

typedef __attribute__((ext_vector_type(8))) short bf16x8;
typedef __attribute__((ext_vector_type(4))) float f32x4;

__device__ __forceinline__ float lrelu(float x) { return x >= 0.0f ? x : 0.01f * x; }

// RNE float -> bf16 bits
__device__ __forceinline__ unsigned short f2bf(float x) {
    unsigned u = __float_as_uint(x);
    unsigned r = ((u >> 16) & 1u) + 0x7fffu;
    return (unsigned short)((u + r) >> 16);
}
__device__ __forceinline__ float bf2f(unsigned short h) {
    return __uint_as_float(((unsigned)h) << 16);
}

// ---------------------------------------------------------------------------
// btsplit: B [K][N] fp32 row-major  ->  T [K/32][N][64] shorts:
//   per (ktile,col): parts 0..3 = hi bf16 of k-groups 0..3 (8 k each),
//                    parts 4..7 = lo bf16 of k-groups 0..3.
// ---------------------------------------------------------------------------
template<int N>
__global__ __launch_bounds__(256) void btsplit_kernel(
    const float* __restrict__ B, short* __restrict__ T)
{
    __shared__ float tile[32][N + 1];
    const int kt = blockIdx.x;
    const int tid = threadIdx.x;
    constexpr int NF4 = 32 * N / 4;
    for (int i = tid; i < NF4; i += 256) {
        const int r = i / (N / 4), c4 = (i % (N / 4)) * 4;
        const float4 v = *reinterpret_cast<const float4*>(&B[((size_t)kt * 32 + r) * N + c4]);
        tile[r][c4 + 0] = v.x; tile[r][c4 + 1] = v.y;
        tile[r][c4 + 2] = v.z; tile[r][c4 + 3] = v.w;
    }
    __syncthreads();
    for (int u = tid; u < 8 * N; u += 256) {
        const int c = u >> 3, part = u & 7, g = part & 3;
        bf16x8 o;
#pragma unroll
        for (int j = 0; j < 8; ++j) {
            const float x = tile[g * 8 + j][c];
            const unsigned short h = f2bf(x);
            if (part < 4) o[j] = (short)h;
            else          o[j] = (short)f2bf(x - bf2f(h));
        }
        *reinterpret_cast<bf16x8*>(&T[((size_t)kt * N + c) * 64 + part * 8]) = o;
    }
}

// ---------------------------------------------------------------------------
// Split-bf16 MFMA GEMM: P[ks][M][BN] = G[tile,kchunk] @ B, with
//   G fp32 (streamed, converted to hi/lo bf16 on the fly, LDS double-buffered,
//   XOR-slot swizzle), B pre-split in T (L2-resident, loaded per-fragment).
// C = Gh.Bh + Gh.Bl + Gl.Bh  (Gl.Bl dropped, ~2^-18 relative)
// 512 threads = 8 waves (2M x 4N), per-wave tile 64 x (BN/4).
// ---------------------------------------------------------------------------
template<int BN>
__global__ __launch_bounds__(512, 2) void gemm_mfma(
    const float* __restrict__ G, int ldg,
    const short* __restrict__ T,
    float* __restrict__ P, int M, int K, int KS)
{
    constexpr int NB = BN / 64;       // 16-col fragments per wave (192->3, 64->1)
    const int tilesM = M >> 7;
    const int bm = (blockIdx.x % tilesM) << 7;
    const int ks = blockIdx.x / tilesM;
    const int Kc = K / KS;
    const int k0 = ks * Kc;
    const int steps = Kc >> 5;

    __shared__ short As[2][128 * 64];   // [buf][row 0..127][hi 32 | lo 32], slot-swizzled

    const int tid = threadIdx.x;
    // staging map: thread -> (row, k-group of 8)
    const int sr = tid >> 2;
    const int sq = tid & 3;
    const float* gp = G + (size_t)(bm + sr) * ldg + k0 + sq * 8;
    const int wslot = (sq ^ (sr & 7)) << 3;          // hi short-offset within row

    // compute map
    const int w = tid >> 6, lane = tid & 63;
    const int wm = w >> 2, wn = w & 3;
    const int lr = lane & 15, ls = lane >> 4;

    f32x4 acc[4][NB];
#pragma unroll
    for (int i = 0; i < 4; ++i)
#pragma unroll
        for (int j = 0; j < NB; ++j) acc[i][j] = (f32x4){0.f, 0.f, 0.f, 0.f};

    int aoff[4];   // byte offset of hi A-frag per row-frag
#pragma unroll
    for (int rf = 0; rf < 4; ++rf) {
        const int r = wm * 64 + rf * 16 + lr;
        aoff[rf] = r * 128 + ((ls ^ (r & 7)) << 4);
    }
    int boff[NB];  // short offset within a ktile row-block of T
#pragma unroll
    for (int cf = 0; cf < NB; ++cf) {
        const int c = wn * (BN / 4) + cf * 16 + lr;
        boff[cf] = c * 64 + ls * 8;
    }
    const short* tb = T + (size_t)(k0 >> 5) * BN * 64;

    // ---- prologue: stage step 0 into As[0] ----
    {
        const float4 x0 = *reinterpret_cast<const float4*>(gp);
        const float4 x1 = *reinterpret_cast<const float4*>(gp + 4);
        const float xs[8] = {x0.x, x0.y, x0.z, x0.w, x1.x, x1.y, x1.z, x1.w};
        bf16x8 hv, lv;
#pragma unroll
        for (int j = 0; j < 8; ++j) {
            const unsigned short h = f2bf(xs[j]);
            hv[j] = (short)h;
            lv[j] = (short)f2bf(xs[j] - bf2f(h));
        }
        short* wb = &As[0][sr * 64 + wslot];
        *reinterpret_cast<bf16x8*>(wb) = hv;
        *reinterpret_cast<bf16x8*>(&As[0][(sr * 64 + wslot) ^ 32]) = lv;
    }
    __syncthreads();

    for (int s = 0; s < steps; ++s) {
        const int p = s & 1;
        // B fragments (global, L2-hit)
        bf16x8 bh[NB], bl[NB];
        const short* tbs = tb + (size_t)s * BN * 64;
#pragma unroll
        for (int cf = 0; cf < NB; ++cf) {
            bh[cf] = *reinterpret_cast<const bf16x8*>(tbs + boff[cf]);
            bl[cf] = *reinterpret_cast<const bf16x8*>(tbs + boff[cf] + 32);
        }
        // A(t+1) global loads (HBM), consumed at end of iter
        float4 x0, x1;
        const bool more = (s + 1 < steps);
        if (more) {
            const float* g2 = gp + (size_t)(s + 1) * 32;
            x0 = *reinterpret_cast<const float4*>(g2);
            x1 = *reinterpret_cast<const float4*>(g2 + 4);
        }
        // A fragments from LDS
        bf16x8 ah[4], al[4];
        const char* ab = reinterpret_cast<const char*>(As[p]);
#pragma unroll
        for (int rf = 0; rf < 4; ++rf) {
            ah[rf] = *reinterpret_cast<const bf16x8*>(ab + aoff[rf]);
            al[rf] = *reinterpret_cast<const bf16x8*>(ab + (aoff[rf] ^ 64));
        }
        // 3-product split MFMA
#pragma unroll
        for (int rf = 0; rf < 4; ++rf)
#pragma unroll
            for (int cf = 0; cf < NB; ++cf) {
                acc[rf][cf] = __builtin_amdgcn_mfma_f32_16x16x32_bf16(ah[rf], bh[cf], acc[rf][cf], 0, 0, 0);
                acc[rf][cf] = __builtin_amdgcn_mfma_f32_16x16x32_bf16(ah[rf], bl[cf], acc[rf][cf], 0, 0, 0);
                acc[rf][cf] = __builtin_amdgcn_mfma_f32_16x16x32_bf16(al[rf], bh[cf], acc[rf][cf], 0, 0, 0);
            }
        // stage A(t+1) into the other buffer
        if (more) {
            const float xs[8] = {x0.x, x0.y, x0.z, x0.w, x1.x, x1.y, x1.z, x1.w};
            bf16x8 hv, lv;
#pragma unroll
            for (int j = 0; j < 8; ++j) {
                const unsigned short h = f2bf(xs[j]);
                hv[j] = (short)h;
                lv[j] = (short)f2bf(xs[j] - bf2f(h));
            }
            short* base = As[p ^ 1];
            *reinterpret_cast<bf16x8*>(&base[sr * 64 + wslot]) = hv;
            *reinterpret_cast<bf16x8*>(&base[(sr * 64 + wslot) ^ 32]) = lv;
        }
        __syncthreads();
    }

    // ---- epilogue: write partials ----
    float* Pp = P + (size_t)ks * M * BN + (size_t)bm * BN;
#pragma unroll
    for (int rf = 0; rf < 4; ++rf)
#pragma unroll
        for (int cf = 0; cf < NB; ++cf) {
            const int col = wn * (BN / 4) + cf * 16 + lr;
#pragma unroll
            for (int j = 0; j < 4; ++j) {
                const int row = wm * 64 + rf * 16 + ls * 4 + j;
                Pp[(size_t)row * BN + col] = acc[rf][cf][j];
            }
        }
}

// C[r, 0:N] (ldc) = sum_s P[s][r][0:N]
__global__ __launch_bounds__(256) void reduce_partials(
    const float* __restrict__ P, float* __restrict__ C,
    int M, int N, int KS, int ldc)
{
    const int total4 = (M * N) >> 2;
    const int n4 = N >> 2;
    for (int idx4 = blockIdx.x * 256 + threadIdx.x; idx4 < total4; idx4 += gridDim.x * 256) {
        const int r = idx4 / n4;
        const int c = (idx4 % n4) * 4;
        float4 s = make_float4(0.f, 0.f, 0.f, 0.f);
        for (int si = 0; si < KS; ++si) {
            const float4 v = *reinterpret_cast<const float4*>(&P[((size_t)si * M + r) * N + c]);
            s.x += v.x; s.y += v.y; s.z += v.z; s.w += v.w;
        }
        *reinterpret_cast<float4*>(&C[(size_t)r * ldc + c]) = s;
    }
}

// Encoder stage2: out = leaky( leaky(sum_s P + b1) @ w2 + b2 ), 64-row blocks
__global__ __launch_bounds__(256) void enc2_kernel(
    const float* __restrict__ P, int KS,
    const float* __restrict__ b1, const float* __restrict__ w2,
    const float* __restrict__ b2, float* __restrict__ out,
    int ldo, int colOff, int Mrows)
{
    __shared__ float Hs[64][68];
    __shared__ float W2s[64][64];
    const int tid = threadIdx.x;
    const int bm = blockIdx.x * 64;
#pragma unroll
    for (int w = 0; w < 4; ++w) {
        const int f4i = tid + w * 256;
        const int rr = f4i >> 4, cc = (f4i & 15) * 4;
        *reinterpret_cast<float4*>(&W2s[rr][cc]) =
            *reinterpret_cast<const float4*>(&w2[rr * 64 + cc]);
    }
#pragma unroll
    for (int w = 0; w < 4; ++w) {
        const int f4i = tid + w * 256;
        const int rr = f4i >> 4, cc = (f4i & 15) * 4;
        float4 s = make_float4(0.f, 0.f, 0.f, 0.f);
        for (int si = 0; si < KS; ++si) {
            const float4 v = *reinterpret_cast<const float4*>(
                &P[((size_t)si * Mrows + bm + rr) * 64 + cc]);
            s.x += v.x; s.y += v.y; s.z += v.z; s.w += v.w;
        }
        s.x = lrelu(s.x + b1[cc + 0]);
        s.y = lrelu(s.y + b1[cc + 1]);
        s.z = lrelu(s.z + b1[cc + 2]);
        s.w = lrelu(s.w + b1[cc + 3]);
        Hs[cc + 0][rr] = s.x; Hs[cc + 1][rr] = s.y;
        Hs[cc + 2][rr] = s.z; Hs[cc + 3][rr] = s.w;
    }
    __syncthreads();
    const int tcol = tid & 15, trow = tid >> 4;
    float acc[4][4];
#pragma unroll
    for (int i = 0; i < 4; ++i)
#pragma unroll
        for (int j = 0; j < 4; ++j) acc[i][j] = 0.0f;
#pragma unroll 8
    for (int e = 0; e < 64; ++e) {
        const float4 a4 = *reinterpret_cast<const float4*>(&Hs[e][trow * 4]);
        const float4 b4 = *reinterpret_cast<const float4*>(&W2s[e][tcol * 4]);
        const float aa[4] = {a4.x, a4.y, a4.z, a4.w};
#pragma unroll
        for (int i = 0; i < 4; ++i) {
            acc[i][0] = fmaf(aa[i], b4.x, acc[i][0]);
            acc[i][1] = fmaf(aa[i], b4.y, acc[i][1]);
            acc[i][2] = fmaf(aa[i], b4.z, acc[i][2]);
            acc[i][3] = fmaf(aa[i], b4.w, acc[i][3]);
        }
    }
    const int cbase = tcol * 4;
#pragma unroll
    for (int i = 0; i < 4; ++i) {
        const int row = bm + trow * 4 + i;
        float4 v;
        v.x = lrelu(acc[i][0] + b2[cbase + 0]);
        v.y = lrelu(acc[i][1] + b2[cbase + 1]);
        v.z = lrelu(acc[i][2] + b2[cbase + 2]);
        v.w = lrelu(acc[i][3] + b2[cbase + 3]);
        *reinterpret_cast<float4*>(&out[(size_t)row * ldo + colOff + cbase]) = v;
    }
}

// W_sum[e][j] = sum_h w_cat[h*64+e][j]
__global__ __launch_bounds__(256) void wsum_kernel(
    const float* __restrict__ wcat, float* __restrict__ W)
{
    const int idx = blockIdx.x * 256 + threadIdx.x;
    const int e = idx >> 6, j = idx & 63;
    W[idx] = wcat[e * 64 + j] + wcat[(64 + e) * 64 + j]
           + wcat[(128 + e) * 64 + j] + wcat[(192 + e) * 64 + j];
}

// g = emb + 0.36 * rownorm( (0.5*(ids[0]+ids[1])) @ W_sum ); wave per row
__global__ __launch_bounds__(256) void g0_kernel(
    const float* __restrict__ ids, const float* __restrict__ emb,
    const float* __restrict__ W, float* __restrict__ outA,
    float* __restrict__ outB, int n)
{
    __shared__ float Ws[64][64];
    __shared__ float rowbuf[4][64];
    const int tid = threadIdx.x;
#pragma unroll
    for (int w = 0; w < 4; ++w) {
        const int f4i = tid + w * 256;
        const int rr = f4i >> 4, cc = (f4i & 15) * 4;
        *reinterpret_cast<float4*>(&Ws[rr][cc]) =
            *reinterpret_cast<const float4*>(&W[rr * 64 + cc]);
    }
    const int wv = tid >> 6, lane = tid & 63;
    const int r = blockIdx.x * 4 + wv;
    const float avg = 0.5f * (ids[(size_t)r * 64 + lane] + ids[((size_t)n + r) * 64 + lane]);
    rowbuf[wv][lane] = avg;
    __syncthreads();
    float acc = 0.0f;
#pragma unroll 8
    for (int e = 0; e < 64; ++e) acc = fmaf(rowbuf[wv][e], Ws[e][lane], acc);
    float ss = acc * acc;
#pragma unroll
    for (int o = 32; o > 0; o >>= 1) ss += __shfl_xor(ss, o);
    const float val = emb[(size_t)r * 64 + lane] + 0.36f * acc / fmaxf(sqrtf(ss), 1e-12f);
    outA[(size_t)r * 64 + lane] = val;
    if (outB != nullptr) outB[(size_t)r * 192 + 128 + lane] = val;
}

// in-place row softmax over 64 columns; wave per row
__global__ __launch_bounds__(256) void softmax64_kernel(float* __restrict__ p, int ld)
{
    const int lane = threadIdx.x & 63;
    const int r = blockIdx.x * 4 + (threadIdx.x >> 6);
    float* row = p + (size_t)r * ld;
    const float x = row[lane];
    float m = x;
#pragma unroll
    for (int o = 32; o > 0; o >>= 1) m = fmaxf(m, __shfl_xor(m, o));
    const float e = expf(x - m);
    float s = e;
#pragma unroll
    for (int o = 32; o > 0; o >>= 1) s += __shfl_xor(s, o);
    row[lane] = e / s;
}

__global__ __launch_bounds__(256) void final_user_kernel(
    const float* __restrict__ ug0, const float* __restrict__ ufA,
    const float* __restrict__ ufB, float* __restrict__ out)
{
    const int lane = threadIdx.x & 63;
    const int r = blockIdx.x * 4 + (threadIdx.x >> 6);
    const size_t r64 = (size_t)r * 64 + lane;
    const size_t r192 = (size_t)r * 192;
    const float g0 = ug0[r64];
    const float g1 = ufA[r192 + 128 + lane];
    const float g2 = ufB[r192 + 128 + lane];
    const float f0 = ufB[r192 + lane];
    const float f1 = ufB[r192 + 64 + lane];
    float s0 = f0 * f0, s1 = f1 * f1;
#pragma unroll
    for (int o = 32; o > 0; o >>= 1) { s0 += __shfl_xor(s0, o); s1 += __shfl_xor(s1, o); }
    const float val = (g0 + g1 + g2) * (1.0f / 3.0f)
        + 0.02f * (f0 / fmaxf(sqrtf(s0), 1e-12f) + f1 / fmaxf(sqrtf(s1), 1e-12f));
    out[O1 + r64] = val;
    out[O5 + r64] = val;
    out[O4 + r64] = f0;
    out[O4 + UD + r64] = f1;
}

__global__ __launch_bounds__(256) void final_item_kernel(
    const float* __restrict__ ig0, const float* __restrict__ ifB,
    const float* __restrict__ ifA, float* __restrict__ out)
{
    const int lane = threadIdx.x & 63;
    const int r = blockIdx.x * 4 + (threadIdx.x >> 6);
    const size_t r64 = (size_t)r * 64 + lane;
    const size_t r192 = (size_t)r * 192;
    const float g0 = ig0[r64];
    const float g1 = ifB[r192 + 128 + lane];
    const float g2 = ifA[r192 + 128 + lane];
    const float f0 = ifA[r192 + lane];
    const float f1 = ifA[r192 + 64 + lane];
    float s0 = f0 * f0, s1 = f1 * f1;
#pragma unroll
    for (int o = 32; o > 0; o >>= 1) { s0 += __shfl_xor(s0, o); s1 += __shfl_xor(s1, o); }
    const float val = (g0 + g1 + g2) * (1.0f / 3.0f)
        + 0.02f * (f0 / fmaxf(sqrtf(s0), 1e-12f) + f1 / fmaxf(sqrtf(s1), 1e-12f));
    out[O2 + r64] = val;
    out[O6 + r64] = val;
    out[O3 + r64] = f0;
    out[O3 + IDD + r64] = f1;
}

extern "C" void kernel_launch(void* const* d_in, const int* in_sizes, int n_in,
                              void* d_out, int out_size, void* d_ws, size_t ws_size,
                              hipStream_t stream)
{
    (void)in_sizes; (void)n_in; (void)out_size; (void)ws_size;
    const float* ui   = (const float*)d_in[0];
    const float* iu   = (const float*)d_in[1];
    const float* mmui = (const float*)d_in[2];
    const float* mmiu = (const float*)d_in[3];
    const float* f0   = (const float*)d_in[4];
    const float* f1   = (const float*)d_in[5];
    const float* e0w1 = (const float*)d_in[6];
    const float* e0b1 = (const float*)d_in[7];
    const float* e0w2 = (const float*)d_in[8];
    const float* e0b2 = (const float*)d_in[9];
    const float* e1w1 = (const float*)d_in[10];
    const float* e1b1 = (const float*)d_in[11];
    const float* e1w2 = (const float*)d_in[12];
    const float* e1b2 = (const float*)d_in[13];
    const float* uemb = (const float*)d_in[14];
    const float* iemb = (const float*)d_in[15];
    /* d_in[16] = w_q is mathematically unused (attention collapses) */
    const float* wcat = (const float*)d_in[17];
    float* out = (float*)d_out;
    float* ws  = (float*)d_ws;

    // workspace layout
    float* PART = ws;                                  // 6,291,456 floats
    short* BTS  = (short*)(PART + 6291456);            // 3,145,728 shorts (6.3 MB)
    float* IFA  = (float*)(BTS + 3145728);             // [I][192]
    float* IFB  = IFA + (size_t)I_N * 192;
    float* UFA  = IFB + (size_t)I_N * 192;
    float* UFB  = UFA + (size_t)U_N * 192;
    float* UG0  = UFB + (size_t)U_N * 192;
    float* IG0  = UG0 + (size_t)U_N * 64;
    float* WSUM = IG0 + (size_t)I_N * 64;

    const dim3 b256(256), b512(512);

    wsum_kernel<<<16, b256, 0, stream>>>(wcat, WSUM);

    // ---- encoders -> IFA cols [0:64) and [64:128) ----
    btsplit_kernel<64><<<4096 / 32, b256, 0, stream>>>(e0w1, BTS);
    gemm_mfma<64><<<(I_N / 128) * 8, b512, 0, stream>>>(f0, 4096, BTS, PART, I_N, 4096, 8);
    enc2_kernel<<<I_N / 64, b256, 0, stream>>>(PART, 8, e0b1, e0w2, e0b2, IFA, 192, 0, I_N);
    btsplit_kernel<64><<<384 / 32, b256, 0, stream>>>(e1w1, BTS);
    gemm_mfma<64><<<(I_N / 128) * 2, b512, 0, stream>>>(f1, 384, BTS, PART, I_N, 384, 2);
    enc2_kernel<<<I_N / 64, b256, 0, stream>>>(PART, 2, e1b1, e1w2, e1b2, IFA, 192, 64, I_N);

    // ---- id-graph matmuls -> user_ids (O7), item_ids (O8) ----
    btsplit_kernel<64><<<I_N / 32, b256, 0, stream>>>(iemb, BTS);
    for (int m = 0; m < 2; ++m) {
        gemm_mfma<64><<<(U_N / 128) * 4, b512, 0, stream>>>(
            mmui + (size_t)m * U_N * I_N, I_N, BTS, PART, U_N, I_N, 4);
        reduce_partials<<<512, b256, 0, stream>>>(PART, out + O7 + (size_t)m * UD, U_N, 64, 4, 64);
    }
    btsplit_kernel<64><<<U_N / 32, b256, 0, stream>>>(uemb, BTS);
    for (int m = 0; m < 2; ++m) {
        gemm_mfma<64><<<(I_N / 128) * 4, b512, 0, stream>>>(
            mmiu + (size_t)m * I_N * U_N, U_N, BTS, PART, I_N, U_N, 4);
        reduce_partials<<<384, b256, 0, stream>>>(PART, out + O8 + (size_t)m * IDD, I_N, 64, 4, 64);
    }

    // ---- u_g0 / i_g0 ----
    g0_kernel<<<U_N / 4, b256, 0, stream>>>(out + O7, uemb, WSUM, UG0, nullptr, U_N);
    g0_kernel<<<I_N / 4, b256, 0, stream>>>(out + O8, iemb, WSUM, IG0, IFA, I_N);

    // ---- 4 batched graph passes (N=192: [feat_m0 | feat_m1 | g]) ----
    // P1: UFA = ui @ IFA
    btsplit_kernel<192><<<I_N / 32, b256, 0, stream>>>(IFA, BTS);
    gemm_mfma<192><<<(U_N / 128) * 4, b512, 0, stream>>>(ui, I_N, BTS, PART, U_N, I_N, 4);
    reduce_partials<<<1536, b256, 0, stream>>>(PART, UFA, U_N, 192, 4, 192);
    // P2: IFB = iu @ UFA
    btsplit_kernel<192><<<U_N / 32, b256, 0, stream>>>(UFA, BTS);
    gemm_mfma<192><<<(I_N / 128) * 4, b512, 0, stream>>>(iu, U_N, BTS, PART, I_N, U_N, 4);
    reduce_partials<<<1152, b256, 0, stream>>>(PART, IFB, I_N, 192, 4, 192);
    // P3: UFB = ui @ IFB ; softmax u_g2
    btsplit_kernel<192><<<I_N / 32, b256, 0, stream>>>(IFB, BTS);
    gemm_mfma<192><<<(U_N / 128) * 4, b512, 0, stream>>>(ui, I_N, BTS, PART, U_N, I_N, 4);
    reduce_partials<<<1536, b256, 0, stream>>>(PART, UFB, U_N, 192, 4, 192);
    softmax64_kernel<<<U_N / 4, b256, 0, stream>>>(UFB + 128, 192);
    // P4: IFA = iu @ UFB ; softmax i_g2
    btsplit_kernel<192><<<U_N / 32, b256, 0, stream>>>(UFB, BTS);
    gemm_mfma<192><<<(I_N / 128) * 4, b512, 0, stream>>>(iu, U_N, BTS, PART, I_N, U_N, 4);
    reduce_partials<<<1152, b256, 0, stream>>>(PART, IFA, I_N, 192, 4, 192);
    softmax64_kernel<<<I_N / 4, b256, 0, stream>>>(IFA + 128, 192);

    // ---- finals ----
    final_user_kernel<<<U_N / 4, b256, 0, stream>>>(UG0, UFA, UFB, out);
    final_item_kernel<<<I_N / 4, b256, 0, stream>>>(IG0, IFB, IFA, out);
}